// Round 6
// baseline (189.858 us; speedup 1.0000x reference)
//
#include <hip/hip_runtime.h>

// Problem constants
#define NB   4096   // B
#define ND   256    // D
#define N2B  8192   // 2B
#define INV_T 2.0f  // 1/TEMP, TEMP=0.5
#define NPAIR 2080  // 64*65/2 band pairs (128-row bands)
#define NTILE 4160  // NPAIR * 2 col-halves (= 8 XCDs * 520)

typedef __attribute__((ext_vector_type(8))) short bf16x8;
typedef __attribute__((ext_vector_type(4))) float f32x4;

// fp32 -> bf16 (RNE) as raw bits
__device__ __forceinline__ unsigned short f2b(float f) {
  unsigned int u = __float_as_uint(f);
  u = (u + 0x7fffu + ((u >> 16) & 1u)) >> 16;
  return (unsigned short)u;
}
__device__ __forceinline__ float b2f(unsigned short h) {
  return __uint_as_float(((unsigned int)h) << 16);
}

// Kernel A: L2-normalize rows of [x_i; x_j] -> Z (bf16 bits).
//   diagE[zrow] = exp(diag/T); pos[r] = dot(z_i[r], z_j[r]).
__global__ __launch_bounds__(256) void k_normalize(
    const float* __restrict__ xi, const float* __restrict__ xj,
    unsigned short* __restrict__ Z, float* __restrict__ diagE,
    float* __restrict__ pos, float* __restrict__ lossAcc,
    unsigned int* __restrict__ ticket) {
  __shared__ float sh[2][256];
  if (blockIdx.x == 0 && threadIdx.x == 0) { *lossAcc = 0.0f; *ticket = 0u; }
  int wave = threadIdx.x >> 6, lane = threadIdx.x & 63;
  int r = (int)blockIdx.x * 2 + (wave & 1);  // row in [0, NB)
  bool isJ = wave >= 2;
  const float* src = (isJ ? xj : xi) + (size_t)r * ND;
  int zrow = r + (isJ ? NB : 0);

  float4 v = *(const float4*)(src + lane * 4);
  float ss = v.x * v.x + v.y * v.y + v.z * v.z + v.w * v.w;
#pragma unroll
  for (int m = 1; m < 64; m <<= 1) ss += __shfl_xor(ss, m, 64);
  float scale = 1.0f / fmaxf(sqrtf(ss), 1e-12f);
  unsigned short h0 = f2b(v.x * scale), h1 = f2b(v.y * scale);
  unsigned short h2 = f2b(v.z * scale), h3 = f2b(v.w * scale);
  ushort4 st; st.x = h0; st.y = h1; st.z = h2; st.w = h3;
  *(ushort4*)(Z + (size_t)zrow * ND + lane * 4) = st;

  float f0 = b2f(h0), f1 = b2f(h1), f2 = b2f(h2), f3 = b2f(h3);
  float d = f0 * f0 + f1 * f1 + f2 * f2 + f3 * f3;
#pragma unroll
  for (int m = 1; m < 64; m <<= 1) d += __shfl_xor(d, m, 64);
  if (lane == 0) diagE[zrow] = __expf(d * INV_T);

  if (isJ) {
    float* s = sh[wave & 1] + lane * 4;
    s[0] = f0; s[1] = f1; s[2] = f2; s[3] = f3;
  }
  __syncthreads();
  if (!isJ) {
    const float* s = sh[wave] + lane * 4;
    float p = f0 * s[0] + f1 * s[1] + f2 * s[2] + f3 * s[3];
#pragma unroll
    for (int m = 1; m < 64; m <<= 1) p += __shfl_xor(p, m, 64);
    if (lane == 0) pos[r] = p;
  }
}

// Kernel B: symmetric triangular GEMM, WAVE-INDEPENDENT (no LDS staging).
// ROUND-6: five structurally different staged variants all pinned at
// 41-45 us with every pipe <30% busy. The invariant was global_load_lds
// staging + vmcnt(0) drains + multi-wave barriers — on data that is
// L2-RESIDENT (Z = 4 MiB = one XCD L2). Catalog common-mistake #7: do not
// stage cache-fit data. Now: direct global->reg fragment loads (A and B
// identical verified 16-row x 64B pattern; the LDS XOR round-trip reduced
// to global chunk kk*4+quad), no barriers in the K-loop, waves fully
// decoupled; compiler pipelines loads across the unrolled K-loop.
// Tile = 128 rows (band I) x 64 cols (half h of band J); 4 waves x 32 rows.
// 4160 tiles = 2080 pairs x 2 halves = 8*520 XCD-bijective, supertile-
// ordered (round-2 verified) for L2 locality.
// P is TRANSPOSED: P[slot][row], 128 slots. Row r in band i receives:
//   col-credits  at slots I in [0,i)   (from tiles (I, i, h_r), I<i)
//   row-partials at slots 2J+h in [2i,128)  (from tiles (i, J, h), J>=i)
// Gap [i,2i) is never written or read (poison-safe). Every slot written
// once -> no atomics, no zero-init. Diag tiles (I==J) compute full 128x64
// (transpose contribution is inside the row sums) and write no credit.
__global__ __launch_bounds__(256, 4) void k_pair(
    const unsigned short* __restrict__ Z, float* __restrict__ P) {
  __shared__ float colred[4][64];  // 1 KiB, single end-of-block reduce

  int tid = threadIdx.x;
  int wave = tid >> 6, lane = tid & 63;
  int quad = lane >> 4, c16 = lane & 15;

  // XCD-bijective tile index; pair-major so both halves are adjacent
  int g = ((int)blockIdx.x & 7) * (NTILE / 8) + ((int)blockIdx.x >> 3);
  int pr = g >> 1, h = g & 1;

  // supertile decode of pr -> (I, J), 0 <= I <= J < 64 (round-2 verified):
  // 8x8-band supertiles, diag supertile 36 tiles, off-diag 64.
  int SI = 0, SJ = 0, u = pr;
  bool found = false;
  for (int a = 0; a < 8 && !found; ++a) {
    for (int b = a; b < 8; ++b) {
      int sz = (a == b) ? 36 : 64;
      if (u < sz) { SI = a; SJ = b; found = true; break; }
      u -= sz;
    }
  }
  int ti, tj;
  if (SI == SJ) {
    ti = 0;
    while (u >= 8 - ti) { u -= 8 - ti; ++ti; }
    tj = ti + u;
  } else {
    ti = u >> 3; tj = u & 7;
  }
  int I = SI * 8 + ti, J = SJ * 8 + tj;
  bool diag = (I == J);

  int rowA = I * 128 + wave * 32;   // this wave's 32 A-rows
  int colB = J * 128 + h * 64;      // this block's 64 B-cols

  const unsigned short* Ar0 = Z + (size_t)(rowA + c16) * ND + quad * 8;
  const unsigned short* Ar1 = Ar0 + (size_t)16 * ND;
  const unsigned short* Bc = Z + (size_t)(colB + c16) * ND + quad * 8;

  // K-loop: direct-from-L2 fragment loads, 8 MFMA per kk, zero barriers.
  f32x4 acc[2][4] = {};
#pragma unroll
  for (int kk = 0; kk < 8; ++kk) {
    bf16x8 a0 = *(const bf16x8*)(Ar0 + kk * 32);
    bf16x8 a1 = *(const bf16x8*)(Ar1 + kk * 32);
    bf16x8 bfr[4];
#pragma unroll
    for (int ni = 0; ni < 4; ++ni)
      bfr[ni] = *(const bf16x8*)(Bc + (size_t)ni * 16 * ND + kk * 32);
#pragma unroll
    for (int ni = 0; ni < 4; ++ni)
      acc[0][ni] = __builtin_amdgcn_mfma_f32_16x16x32_bf16(a0, bfr[ni],
                                                           acc[0][ni], 0, 0, 0);
#pragma unroll
    for (int ni = 0; ni < 4; ++ni)
      acc[1][ni] = __builtin_amdgcn_mfma_f32_16x16x32_bf16(a1, bfr[ni],
                                                           acc[1][ni], 0, 0, 0);
  }

  // fused exp; row partials (this tile's 64 cols) + col partials (32 rows).
  // C/D layout: out_row = quad*4 + r (+ rg*16), out_col = ni*16 + c16.
  float rs[2][4] = {{0.0f, 0.0f, 0.0f, 0.0f}, {0.0f, 0.0f, 0.0f, 0.0f}};
  float csum[4] = {0.0f, 0.0f, 0.0f, 0.0f};
#pragma unroll
  for (int rg = 0; rg < 2; ++rg)
#pragma unroll
    for (int ni = 0; ni < 4; ++ni)
#pragma unroll
      for (int r = 0; r < 4; ++r) {
        float e = __expf(acc[rg][ni][r] * INV_T);
        rs[rg][r] += e;
        csum[ni] += e;
      }

  // row partials: reduce across c16 (the 16 cols of each frag)
#pragma unroll
  for (int m = 1; m <= 8; m <<= 1)
#pragma unroll
    for (int rg = 0; rg < 2; ++rg)
#pragma unroll
      for (int r = 0; r < 4; ++r)
        rs[rg][r] += __shfl_xor(rs[rg][r], m, 64);

#pragma unroll
  for (int rg = 0; rg < 2; ++rg)
#pragma unroll
    for (int r = 0; r < 4; ++r)
      if (c16 == rg * 4 + r) {
        int row = rowA + rg * 16 + quad * 4 + r;
        P[(size_t)(2 * J + h) * N2B + row] = rs[rg][r];
      }

  if (!diag) {
    // col partials: sum this wave's 32 rows (quad halves), then cross-wave
#pragma unroll
    for (int ni = 0; ni < 4; ++ni) {
      csum[ni] += __shfl_xor(csum[ni], 16, 64);
      csum[ni] += __shfl_xor(csum[ni], 32, 64);
    }
    if (lane < 16) {
#pragma unroll
      for (int ni = 0; ni < 4; ++ni) colred[wave][ni * 16 + lane] = csum[ni];
    }
    __syncthreads();  // the block's only barrier
    if (tid < 64) {
      float v = colred[0][tid] + colred[1][tid] + colred[2][tid] +
                colred[3][tid];
      P[(size_t)I * N2B + colB + tid] = v;  // coalesced credit write
    }
  }
}

// Kernel C: 32 blocks x 256 rows. Band i = row>>7; sum clean slot ranges
// [0,i) and [2i,128) of transposed P (coalesced: consecutive threads read
// consecutive rows), subtract diagE, log, subtract pos/T; block-reduce ->
// one atomicAdd; ticketed last block writes out.
__global__ __launch_bounds__(256) void k_final(
    const float* __restrict__ P, const float* __restrict__ diagE,
    const float* __restrict__ pos, float* __restrict__ lossAcc,
    unsigned int* __restrict__ ticket, float* __restrict__ out) {
  __shared__ float red[4];
  int tid = threadIdx.x;
  int wave = tid >> 6, lane = tid & 63;
  int row = (int)blockIdx.x * 256 + tid;
  int i = row >> 7;  // wave-uniform (128-row bands, 64-lane waves)

  float s = 0.0f;
  for (int q = 0; q < i; ++q) s += P[(size_t)q * N2B + row];
  for (int q = 2 * i; q < 128; ++q) s += P[(size_t)q * N2B + row];
  s -= diagE[row];
  float term = __logf(s) - INV_T * pos[row & (NB - 1)];
#pragma unroll
  for (int m = 1; m < 64; m <<= 1) term += __shfl_xor(term, m, 64);
  if (lane == 0) red[wave] = term;
  __syncthreads();
  if (tid == 0) {
    float bs = red[0] + red[1] + red[2] + red[3];
    atomicAdd(lossAcc, bs);
    __threadfence();
    unsigned int old = atomicAdd(ticket, 1u);
    if (old == 31u) {
      float v = atomicAdd(lossAcc, 0.0f);  // atomic read after all adds
      out[0] = v * (1.0f / (float)N2B);
    }
  }
}

extern "C" void kernel_launch(void* const* d_in, const int* in_sizes, int n_in,
                              void* d_out, int out_size, void* d_ws,
                              size_t ws_size, hipStream_t stream) {
  const float* xi = (const float*)d_in[0];
  const float* xj = (const float*)d_in[1];
  float* out = (float*)d_out;
  char* ws = (char*)d_ws;
  unsigned short* Z = (unsigned short*)ws;           // 4 MiB
  float* P = (float*)(ws + (4u << 20));              // 128*8192*4 = 4 MiB
  float* pos = (float*)(ws + (8u << 20));            // 16 KiB
  float* diagE = (float*)(ws + (8u << 20) + 65536);  // 32 KiB
  float* lossAcc = (float*)(ws + (8u << 20) + 131072);
  unsigned int* ticket = (unsigned int*)(ws + (8u << 20) + 131072 + 64);

  k_normalize<<<dim3(NB / 2), dim3(256), 0, stream>>>(xi, xj, Z, diagE, pos,
                                                      lossAcc, ticket);
  k_pair<<<dim3(NTILE), dim3(256), 0, stream>>>(Z, P);
  k_final<<<dim3(32), dim3(256), 0, stream>>>(P, diagE, pos, lossAcc, ticket,
                                              out);
}

// Round 7
// 117.492 us; speedup vs baseline: 1.6159x; 1.6159x over previous
//
#include <hip/hip_runtime.h>

// Problem constants
#define NB   4096   // B
#define ND   256    // D
#define N2B  8192   // 2B
#define INV_T 2.0f  // 1/TEMP, TEMP=0.5
#define NBAND 32    // 256-row bands
#define NSLOT 32    // P slots per row
#define NTILE 528   // 32*33/2 band pairs (= 8 XCDs * 66)

typedef __attribute__((ext_vector_type(8))) short bf16x8;
typedef __attribute__((ext_vector_type(4))) float f32x4;

__device__ __forceinline__ void gload_lds16(const void* g, void* l) {
  __builtin_amdgcn_global_load_lds(
      (const __attribute__((address_space(1))) void*)g,
      (__attribute__((address_space(3))) void*)l, 16, 0, 0);
}

// fp32 -> bf16 (RNE) as raw bits
__device__ __forceinline__ unsigned short f2b(float f) {
  unsigned int u = __float_as_uint(f);
  u = (u + 0x7fffu + ((u >> 16) & 1u)) >> 16;
  return (unsigned short)u;
}
__device__ __forceinline__ float b2f(unsigned short h) {
  return __uint_as_float(((unsigned int)h) << 16);
}

// Kernel A: L2-normalize rows of [x_i; x_j] -> Z (bf16 bits).
__global__ __launch_bounds__(256) void k_normalize(
    const float* __restrict__ xi, const float* __restrict__ xj,
    unsigned short* __restrict__ Z, float* __restrict__ diagE,
    float* __restrict__ pos, float* __restrict__ lossAcc,
    unsigned int* __restrict__ ticket) {
  __shared__ float sh[2][256];
  if (blockIdx.x == 0 && threadIdx.x == 0) { *lossAcc = 0.0f; *ticket = 0u; }
  int wave = threadIdx.x >> 6, lane = threadIdx.x & 63;
  int r = (int)blockIdx.x * 2 + (wave & 1);  // row in [0, NB)
  bool isJ = wave >= 2;
  const float* src = (isJ ? xj : xi) + (size_t)r * ND;
  int zrow = r + (isJ ? NB : 0);

  float4 v = *(const float4*)(src + lane * 4);
  float ss = v.x * v.x + v.y * v.y + v.z * v.z + v.w * v.w;
#pragma unroll
  for (int m = 1; m < 64; m <<= 1) ss += __shfl_xor(ss, m, 64);
  float scale = 1.0f / fmaxf(sqrtf(ss), 1e-12f);
  unsigned short h0 = f2b(v.x * scale), h1 = f2b(v.y * scale);
  unsigned short h2 = f2b(v.z * scale), h3 = f2b(v.w * scale);
  ushort4 st; st.x = h0; st.y = h1; st.z = h2; st.w = h3;
  *(ushort4*)(Z + (size_t)zrow * ND + lane * 4) = st;

  float f0 = b2f(h0), f1 = b2f(h1), f2 = b2f(h2), f3 = b2f(h3);
  float d = f0 * f0 + f1 * f1 + f2 * f2 + f3 * f3;
#pragma unroll
  for (int m = 1; m < 64; m <<= 1) d += __shfl_xor(d, m, 64);
  if (lane == 0) diagE[zrow] = __expf(d * INV_T);

  if (isJ) {
    float* s = sh[wave & 1] + lane * 4;
    s[0] = f0; s[1] = f1; s[2] = f2; s[3] = f3;
  }
  __syncthreads();
  if (!isJ) {
    const float* s = sh[wave] + lane * 4;
    float p = f0 * s[0] + f1 * s[1] + f2 * s[2] + f3 * s[3];
#pragma unroll
    for (int m = 1; m < 64; m <<= 1) p += __shfl_xor(p, m, 64);
    if (lane == 0) pos[r] = p;
  }
}

// Kernel B: symmetric triangular GEMM, 256x256 tiles.
// ROUND-7: consolidated model from rounds 2-6 — effective L2->CU delivered
// BW for this access mix is ~5-6 TB/s device-wide (round 2: 266 MB/44.7us
// = 5.95 TB/s; round 5: 167 MB/41us with XCD imbalance; round 6's direct
// loads: worse). The lever is bytes moved: traffic ~= 17.2 GB*(1/Ta+1/Tb).
// T=128 -> 268 MB; T=256 -> 134 MB (this kernel).
//   - 32 bands x 256 rows; 528 pairs (I<=J) = 8 XCDs x 66, bijective,
//     supertile-ordered (4x4-band groups: 8 diag x10 + 28 off x16 = 528)
//     -> per-XCD live window ~2.5 MB -> L2-resident (round 2 verified).
//   - UNIFORM work per block (fixes round 5's I-major XCD imbalance).
//   - 256 thr / 4 waves; wave holds 64 A-rows in regs (afr[4][8], loads
//     are 64B-line-perfect); B streams as 4 x (64-row, 32 KiB) chunks
//     through a 2x32 KiB LDS dbuf (verified XOR swizzle), round-5 T3-lite
//     pipeline: STAGE(c+1) before compute(c), one vmcnt(0)+barrier/chunk.
// P[row][32 slots]: row r in band i gets col-credits at slots [0,i) (from
// blocks (I',i)) and row-partials at [i,32) (from blocks (i,J), diag block
// computes full 256x256 so its row-partial covers band i itself). Every
// slot written exactly once -> no atomics, no zero-init.
__global__ __launch_bounds__(256, 2) void k_sym(
    const unsigned short* __restrict__ Z, float* __restrict__ P) {
  __shared__ alignas(16) unsigned short Bsh[2][64 * ND];  // 2 x 32 KiB
  __shared__ float colred[2][4][64];                      // 2 KiB

  int tid = threadIdx.x;
  int wave = tid >> 6, lane = tid & 63;
  int quad = lane >> 4, c16 = lane & 15;
  int lr1 = lane >> 5, cs = lane & 31;

  // XCD-bijective remap (528 = 8*66), then supertile decode -> (I, J)
  int g = ((int)blockIdx.x & 7) * (NTILE / 8) + ((int)blockIdx.x >> 3);
  int SI = 0, SJ = 0, u = g;
  bool found = false;
  for (int a = 0; a < 8 && !found; ++a) {
    for (int b = a; b < 8; ++b) {
      int sz = (a == b) ? 10 : 16;
      if (u < sz) { SI = a; SJ = b; found = true; break; }
      u -= sz;
    }
  }
  int ti, tj;
  if (SI == SJ) {  // triangular decode over 4: 0 <= ti <= tj < 4
    ti = 0;
    while (u >= 4 - ti) { u -= 4 - ti; ++ti; }
    tj = ti + u;
  } else {
    ti = u >> 2; tj = u & 3;
  }
  int I = SI * 4 + ti, J = SJ * 4 + tj;  // 256-row band indices, I <= J
  bool diag = (I == J);

  int rowA = I * 256, colB0 = J * 256;

  // A fragments: wave owns 64 rows, full K, direct global->reg.
  // Each load instruction covers 16 rows x 64B fully (line-perfect).
  bf16x8 afr[4][8];
  int wrowA = rowA + wave * 64;
#pragma unroll
  for (int rg = 0; rg < 4; ++rg)
#pragma unroll
    for (int kk = 0; kk < 8; ++kk)
      afr[rg][kk] = *(const bf16x8*)(Z + (size_t)(wrowA + rg * 16 + c16) * ND +
                                     kk * 32 + quad * 8);

  // B chunk stager: chunk c = 64 Z-rows (64 sim-cols), 32 KiB -> half h.
  // Verified XOR chunk swizzle: slot cs gets global chunk cs^(row&31).
  auto STAGE = [&](int c, int h) {
    int base = colB0 + c * 64;
#pragma unroll
    for (int j = 0; j < 8; ++j) {
      int r0 = wave * 16 + j * 2;  // wave-uniform base (2 rows / call)
      int row = r0 + lr1;
      int gc = cs ^ (row & 31);
      gload_lds16(Z + (size_t)(base + row) * ND + gc * 8, &Bsh[h][r0 * ND]);
    }
  };

  STAGE(0, 0);
  asm volatile("s_waitcnt vmcnt(0)" ::: "memory");
  __syncthreads();

  float rs[4][4];
#pragma unroll
  for (int rg = 0; rg < 4; ++rg)
#pragma unroll
    for (int r = 0; r < 4; ++r) rs[rg][r] = 0.0f;

  for (int c = 0; c < 4; ++c) {
    int h = c & 1;
    if (c + 1 < 4) STAGE(c + 1, h ^ 1);  // in flight across this phase

    // compute chunk c: 128 MFMA/wave (64 A-rows x 64 cols, K=256)
    f32x4 acc[4][4] = {};
    __builtin_amdgcn_s_setprio(1);
#pragma unroll
    for (int kk = 0; kk < 8; ++kk) {
      bf16x8 bfr[4];
#pragma unroll
      for (int ni = 0; ni < 4; ++ni) {
        int row = ni * 16 + c16;
        int slot = (kk * 4 + quad) ^ (row & 31);
        bfr[ni] = *(const bf16x8*)&Bsh[h][row * ND + slot * 8];
      }
#pragma unroll
      for (int rg = 0; rg < 4; ++rg)
#pragma unroll
        for (int ni = 0; ni < 4; ++ni)
          acc[rg][ni] = __builtin_amdgcn_mfma_f32_16x16x32_bf16(
              afr[rg][kk], bfr[ni], acc[rg][ni], 0, 0, 0);
    }
    __builtin_amdgcn_s_setprio(0);

    // fused exp; row partials accumulate across chunks; col partials per
    // chunk. C/D: out_row = rg*16 + quad*4 + r, out_col = ni*16 + c16.
    float cs_[4] = {0.0f, 0.0f, 0.0f, 0.0f};
#pragma unroll
    for (int rg = 0; rg < 4; ++rg)
#pragma unroll
      for (int ni = 0; ni < 4; ++ni)
#pragma unroll
        for (int r = 0; r < 4; ++r) {
          float e = __expf(acc[rg][ni][r] * INV_T);
          rs[rg][r] += e;
          cs_[ni] += e;
        }

    // col partial: sum this wave's 64 rows (quad halves), then cross-wave
#pragma unroll
    for (int ni = 0; ni < 4; ++ni) {
      cs_[ni] += __shfl_xor(cs_[ni], 16, 64);
      cs_[ni] += __shfl_xor(cs_[ni], 32, 64);
    }
    if (lane < 16) {
#pragma unroll
      for (int ni = 0; ni < 4; ++ni) colred[h][wave][ni * 16 + lane] = cs_[ni];
    }

    asm volatile("s_waitcnt vmcnt(0)" ::: "memory");  // drain STAGE(c+1)
    __syncthreads();

    // col-credit for chunk c (64 cols), written once per col
    if (!diag && tid < 64) {
      float v = colred[h][0][tid] + colred[h][1][tid] + colred[h][2][tid] +
                colred[h][3][tid];
      P[(size_t)(colB0 + c * 64 + tid) * NSLOT + I] = v;
    }
  }

  // row partials: reduce across c16 (the 16 cols of each frag), write once
#pragma unroll
  for (int m = 1; m <= 8; m <<= 1)
#pragma unroll
    for (int rg = 0; rg < 4; ++rg)
#pragma unroll
      for (int r = 0; r < 4; ++r)
        rs[rg][r] += __shfl_xor(rs[rg][r], m, 64);

#pragma unroll
  for (int rg = 0; rg < 4; ++rg)
#pragma unroll
    for (int r = 0; r < 4; ++r)
      if (c16 == rg * 4 + r) {
        int row = wrowA + rg * 16 + quad * 4 + r;
        P[(size_t)row * NSLOT + J] = rs[rg][r];
      }
}

// Kernel C: 32 blocks x 256 rows. rowsum[r] = sum_{q<32} P[r][q] - diagE[r];
// term = log(rowsum) - pos[r%B]/T. Block-reduce -> one atomicAdd per block;
// ticketed last block writes out = lossAcc / 2B.
__global__ __launch_bounds__(256) void k_final(
    const float* __restrict__ P, const float* __restrict__ diagE,
    const float* __restrict__ pos, float* __restrict__ lossAcc,
    unsigned int* __restrict__ ticket, float* __restrict__ out) {
  __shared__ float red[4];
  int tid = threadIdx.x;
  int wave = tid >> 6, lane = tid & 63;
  int row = (int)blockIdx.x * 256 + tid;

  const float4* Pr = (const float4*)(P + (size_t)row * NSLOT);
  float s = 0.0f;
#pragma unroll
  for (int q = 0; q < 8; ++q) {
    float4 a = Pr[q];
    s += (a.x + a.y) + (a.z + a.w);
  }
  s -= diagE[row];
  float term = __logf(s) - INV_T * pos[row & (NB - 1)];
#pragma unroll
  for (int m = 1; m < 64; m <<= 1) term += __shfl_xor(term, m, 64);
  if (lane == 0) red[wave] = term;
  __syncthreads();
  if (tid == 0) {
    float bs = red[0] + red[1] + red[2] + red[3];
    atomicAdd(lossAcc, bs);
    __threadfence();
    unsigned int old = atomicAdd(ticket, 1u);
    if (old == 31u) {
      float v = atomicAdd(lossAcc, 0.0f);  // atomic read after all adds
      out[0] = v * (1.0f / (float)N2B);
    }
  }
}

extern "C" void kernel_launch(void* const* d_in, const int* in_sizes, int n_in,
                              void* d_out, int out_size, void* d_ws,
                              size_t ws_size, hipStream_t stream) {
  const float* xi = (const float*)d_in[0];
  const float* xj = (const float*)d_in[1];
  float* out = (float*)d_out;
  char* ws = (char*)d_ws;
  unsigned short* Z = (unsigned short*)ws;           // 4 MiB
  float* P = (float*)(ws + (4u << 20));              // 8192*32*4 = 1 MiB
  float* pos = (float*)(ws + (5u << 20));            // 16 KiB
  float* diagE = (float*)(ws + (5u << 20) + 65536);  // 32 KiB
  float* lossAcc = (float*)(ws + (5u << 20) + 131072);
  unsigned int* ticket = (unsigned int*)(ws + (5u << 20) + 131072 + 64);

  k_normalize<<<dim3(NB / 2), dim3(256), 0, stream>>>(xi, xj, Z, diagE, pos,
                                                      lossAcc, ticket);
  k_sym<<<dim3(NTILE), dim3(256), 0, stream>>>(Z, P);
  k_final<<<dim3(32), dim3(256), 0, stream>>>(P, diagE, pos, lossAcc, ticket,
                                              out);
}

// Round 8
// 103.787 us; speedup vs baseline: 1.8293x; 1.1320x over previous
//
#include <hip/hip_runtime.h>

// Problem constants
#define NB   4096   // B
#define ND   256    // D
#define N2B  8192   // 2B
#define INV_T 2.0f  // 1/TEMP, TEMP=0.5
#define NBAND 64    // 128-row bands; P slots per row
#define NTILE 2080  // 64*65/2 triangular band pairs (= 8 XCDs * 260)

typedef __attribute__((ext_vector_type(8))) short bf16x8;
typedef __attribute__((ext_vector_type(4))) float f32x4;

__device__ __forceinline__ void gload_lds16(const void* g, void* l) {
  __builtin_amdgcn_global_load_lds(
      (const __attribute__((address_space(1))) void*)g,
      (__attribute__((address_space(3))) void*)l, 16, 0, 0);
}

// fp32 -> bf16 (RNE) as raw bits
__device__ __forceinline__ unsigned short f2b(float f) {
  unsigned int u = __float_as_uint(f);
  u = (u + 0x7fffu + ((u >> 16) & 1u)) >> 16;
  return (unsigned short)u;
}
__device__ __forceinline__ float b2f(unsigned short h) {
  return __uint_as_float(((unsigned int)h) << 16);
}

// Sum over the 16-lane DPP row via row_ror rotations (VALU, not LDS pipe).
// After ror8/4/2/1 accumulation every lane holds its row's full sum.
__device__ __forceinline__ float row_sum16(float v) {
  int x;
  x = __builtin_amdgcn_update_dpp(0, __float_as_int(v), 0x128, 0xF, 0xF, 0);
  v += __int_as_float(x);  // + ror8
  x = __builtin_amdgcn_update_dpp(0, __float_as_int(v), 0x124, 0xF, 0xF, 0);
  v += __int_as_float(x);  // + ror4
  x = __builtin_amdgcn_update_dpp(0, __float_as_int(v), 0x122, 0xF, 0xF, 0);
  v += __int_as_float(x);  // + ror2
  x = __builtin_amdgcn_update_dpp(0, __float_as_int(v), 0x121, 0xF, 0xF, 0);
  v += __int_as_float(x);  // + ror1
  return v;
}

// Kernel A: L2-normalize rows of [x_i; x_j] -> Z (bf16 bits).
__global__ __launch_bounds__(256) void k_normalize(
    const float* __restrict__ xi, const float* __restrict__ xj,
    unsigned short* __restrict__ Z, float* __restrict__ diagE,
    float* __restrict__ pos, float* __restrict__ lossAcc,
    unsigned int* __restrict__ ticket) {
  __shared__ float sh[2][256];
  if (blockIdx.x == 0 && threadIdx.x == 0) { *lossAcc = 0.0f; *ticket = 0u; }
  int wave = threadIdx.x >> 6, lane = threadIdx.x & 63;
  int r = (int)blockIdx.x * 2 + (wave & 1);  // row in [0, NB)
  bool isJ = wave >= 2;
  const float* src = (isJ ? xj : xi) + (size_t)r * ND;
  int zrow = r + (isJ ? NB : 0);

  float4 v = *(const float4*)(src + lane * 4);
  float ss = v.x * v.x + v.y * v.y + v.z * v.z + v.w * v.w;
#pragma unroll
  for (int m = 1; m < 64; m <<= 1) ss += __shfl_xor(ss, m, 64);
  float scale = 1.0f / fmaxf(sqrtf(ss), 1e-12f);
  unsigned short h0 = f2b(v.x * scale), h1 = f2b(v.y * scale);
  unsigned short h2 = f2b(v.z * scale), h3 = f2b(v.w * scale);
  ushort4 st; st.x = h0; st.y = h1; st.z = h2; st.w = h3;
  *(ushort4*)(Z + (size_t)zrow * ND + lane * 4) = st;

  float f0 = b2f(h0), f1 = b2f(h1), f2 = b2f(h2), f3 = b2f(h3);
  float d = f0 * f0 + f1 * f1 + f2 * f2 + f3 * f3;
#pragma unroll
  for (int m = 1; m < 64; m <<= 1) d += __shfl_xor(d, m, 64);
  if (lane == 0) diagE[zrow] = __expf(d * INV_T);

  if (isJ) {
    float* s = sh[wave & 1] + lane * 4;
    s[0] = f0; s[1] = f1; s[2] = f2; s[3] = f3;
  }
  __syncthreads();
  if (!isJ) {
    const float* s = sh[wave] + lane * 4;
    float p = f0 * s[0] + f1 * s[1] + f2 * s[2] + f3 * s[3];
#pragma unroll
    for (int m = 1; m < 64; m <<= 1) p += __shfl_xor(p, m, 64);
    if (lane == 0) pos[r] = p;
  }
}

// Kernel B: symmetric triangular band GEMM + fused exp / dual reduction.
// ROUND-8: per-CU accounting of R2's counters put the LDS pipe at ~20 us/CU
// (64 ds_read_b128 + 48 shuffle-bpermutes per wave-block + staging), the
// largest single consumer — and explains R3's occupancy null (the pipe is
// per-CU). R7's 256^2 test was confounded by VGPR spills (VGPR=128 cap,
// 18 MB scratch traffic) + 1 blk/CU (66 KiB LDS). Two changes, both on
// proven skeletons:
//  (1) rs row-reduction moved off the LDS pipe: DPP row_ror adds (VALU)
//      replace 32 bpermute-backed shfl_xor per wave.
//  (2) B streamed in 4 x 32-row (16 KiB) chunks through a 2x16 KiB dbuf
//      with R5's proven one-drain-per-chunk pipeline (STAGE(c+1) issued
//      before compute(c)); uniform one-pair-per-block work (fixes R5's
//      XCD imbalance), LDS 34 KiB, VGPR ~115 at the proven (256,2) regime.
// Schedule: R2's verified supertile order (8x8-band supertiles, 36/64
// tiles, XCD-bijective 2080=8*260) -> Z window L2-resident (FETCH 10.4 MB).
// P[row][64]: row r in band i gets col-credits at slots [0,i) and
// row-partials at [i,64); diag pair computes full 128x128 (both triangles
// in row-sums), no credit. Every slot written once -> no atomics/zero-init.
__global__ __launch_bounds__(256, 2) void k_sym(
    const unsigned short* __restrict__ Z, float* __restrict__ P) {
  __shared__ alignas(16) unsigned short Bsh[2][32 * ND];  // 2 x 16 KiB
  __shared__ float colred[2][4][32];                      // 1 KiB

  int tid = threadIdx.x;
  int wave = tid >> 6, lane = tid & 63;
  int quad = lane >> 4, c16 = lane & 15;
  int lr1 = lane >> 5, cs = lane & 31;

  // ---- supertile-major pair index, XCD-contiguous (verified round 2) ----
  int g = ((int)blockIdx.x & 7) * (NTILE / 8) + ((int)blockIdx.x >> 3);
  int SI = 0, SJ = 0, u = g;
  bool found = false;
  for (int a = 0; a < 8 && !found; ++a) {
    for (int b = a; b < 8; ++b) {
      int sz = (a == b) ? 36 : 64;
      if (u < sz) { SI = a; SJ = b; found = true; break; }
      u -= sz;
    }
  }
  int ti, tj;
  if (SI == SJ) {  // triangular decode: 0 <= ti <= tj < 8
    ti = 0;
    while (u >= 8 - ti) { u -= 8 - ti; ++ti; }
    tj = ti + u;
  } else {
    ti = u >> 3; tj = u & 7;
  }
  int I = SI * 8 + ti, J = SJ * 8 + tj;
  bool diag = (I == J);

  int rowA = I * 128, colB0 = J * 128;

  // A fragments: wave owns 32 rows, full K, direct global->reg
  // (16 rows x 64B contiguous per instruction: line-perfect, L2-served).
  bf16x8 afr[2][8];
  int wrow = rowA + wave * 32;
#pragma unroll
  for (int rg = 0; rg < 2; ++rg)
#pragma unroll
    for (int kk = 0; kk < 8; ++kk)
      afr[rg][kk] = *(const bf16x8*)(Z + (size_t)(wrow + rg * 16 + c16) * ND +
                                     kk * 32 + quad * 8);

  // B chunk stager: chunk c = 32 Z-rows (32 sim-cols) = 16 KiB -> half h.
  // Verified XOR chunk swizzle: LDS slot cs holds global chunk cs^row.
  auto STAGE = [&](int c, int h) {
    int base = colB0 + c * 32;
#pragma unroll
    for (int j = 0; j < 4; ++j) {
      int r0 = wave * 8 + j * 2;  // wave-uniform base (2 rows / call)
      int row = r0 + lr1;
      int gc = cs ^ row;          // rows 0..31
      gload_lds16(Z + (size_t)(base + row) * ND + gc * 8, &Bsh[h][r0 * ND]);
    }
  };

  STAGE(0, 0);
  asm volatile("s_waitcnt vmcnt(0)" ::: "memory");
  __syncthreads();

  float rs[2][4];
#pragma unroll
  for (int rg = 0; rg < 2; ++rg)
#pragma unroll
    for (int r = 0; r < 4; ++r) rs[rg][r] = 0.0f;

  for (int c = 0; c < 4; ++c) {
    int h = c & 1;
    if (c + 1 < 4) STAGE(c + 1, h ^ 1);  // in flight across this compute

    // compute chunk c: 32 MFMA/wave (32 A-rows x 32 cols, K=256)
    f32x4 acc[2][2] = {};
    __builtin_amdgcn_s_setprio(1);
#pragma unroll
    for (int kk = 0; kk < 8; ++kk) {
      bf16x8 bfr[2];
#pragma unroll
      for (int ni = 0; ni < 2; ++ni) {
        int row = ni * 16 + c16;
        int slot = (kk * 4 + quad) ^ row;
        bfr[ni] = *(const bf16x8*)&Bsh[h][row * ND + slot * 8];
      }
#pragma unroll
      for (int rg = 0; rg < 2; ++rg)
#pragma unroll
        for (int ni = 0; ni < 2; ++ni)
          acc[rg][ni] = __builtin_amdgcn_mfma_f32_16x16x32_bf16(
              afr[rg][kk], bfr[ni], acc[rg][ni], 0, 0, 0);
    }
    __builtin_amdgcn_s_setprio(0);

    // fused exp; rs accumulates across chunks; csum per chunk.
    // C/D: out_row = rg*16 + quad*4 + r, out_col = ni*16 + c16.
    float csum[2] = {0.0f, 0.0f};
#pragma unroll
    for (int rg = 0; rg < 2; ++rg)
#pragma unroll
      for (int ni = 0; ni < 2; ++ni)
#pragma unroll
        for (int r = 0; r < 4; ++r) {
          float e = __expf(acc[rg][ni][r] * INV_T);
          rs[rg][r] += e;
          csum[ni] += e;
        }

    // col partial: cross-quad sum (2 shuffles), stash in colred
#pragma unroll
    for (int ni = 0; ni < 2; ++ni) {
      csum[ni] += __shfl_xor(csum[ni], 16, 64);
      csum[ni] += __shfl_xor(csum[ni], 32, 64);
    }
    if (lane < 16) {
      colred[h][wave][lane] = csum[0];
      colred[h][wave][16 + lane] = csum[1];
    }

    asm volatile("s_waitcnt vmcnt(0)" ::: "memory");  // STAGE(c+1) landed
    __syncthreads();  // + all reads of Bsh[h] / writes of colred[h] done

    // col-credit for chunk c (32 cols), written once per col
    if (!diag && tid < 32) {
      float v = colred[h][0][tid] + colred[h][1][tid] + colred[h][2][tid] +
                colred[h][3][tid];
      P[(size_t)(colB0 + c * 32 + tid) * NBAND + I] = v;
    }
  }

  // row partials: DPP row-sum over the 16 cols held per lane group (VALU),
  // then one write per row.
#pragma unroll
  for (int rg = 0; rg < 2; ++rg)
#pragma unroll
    for (int r = 0; r < 4; ++r) rs[rg][r] = row_sum16(rs[rg][r]);

#pragma unroll
  for (int rg = 0; rg < 2; ++rg)
#pragma unroll
    for (int r = 0; r < 4; ++r)
      if (c16 == rg * 4 + r) {
        int row = wrow + rg * 16 + quad * 4 + r;
        P[(size_t)row * NBAND + J] = rs[rg][r];
      }
}

// Kernel C: 32 blocks x 256 rows. rowsum[r] = sum_{q<64} P[r][q] - diagE[r];
// term = log(rowsum) - pos[r%B]/T. Block-reduce -> one atomicAdd per block;
// ticketed last block writes out = lossAcc / 2B.
__global__ __launch_bounds__(256) void k_final(
    const float* __restrict__ P, const float* __restrict__ diagE,
    const float* __restrict__ pos, float* __restrict__ lossAcc,
    unsigned int* __restrict__ ticket, float* __restrict__ out) {
  __shared__ float red[4];
  int tid = threadIdx.x;
  int wave = tid >> 6, lane = tid & 63;
  int row = (int)blockIdx.x * 256 + tid;

  const float4* Pr = (const float4*)(P + (size_t)row * NBAND);
  float s = 0.0f;
#pragma unroll
  for (int q = 0; q < 16; ++q) {
    float4 a = Pr[q];
    s += (a.x + a.y) + (a.z + a.w);
  }
  s -= diagE[row];
  float term = __logf(s) - INV_T * pos[row & (NB - 1)];
#pragma unroll
  for (int m = 1; m < 64; m <<= 1) term += __shfl_xor(term, m, 64);
  if (lane == 0) red[wave] = term;
  __syncthreads();
  if (tid == 0) {
    float bs = red[0] + red[1] + red[2] + red[3];
    atomicAdd(lossAcc, bs);
    __threadfence();
    unsigned int old = atomicAdd(ticket, 1u);
    if (old == 31u) {
      float v = atomicAdd(lossAcc, 0.0f);  // atomic read after all adds
      out[0] = v * (1.0f / (float)N2B);
    }
  }
}

extern "C" void kernel_launch(void* const* d_in, const int* in_sizes, int n_in,
                              void* d_out, int out_size, void* d_ws,
                              size_t ws_size, hipStream_t stream) {
  const float* xi = (const float*)d_in[0];
  const float* xj = (const float*)d_in[1];
  float* out = (float*)d_out;
  char* ws = (char*)d_ws;
  unsigned short* Z = (unsigned short*)ws;           // 4 MiB
  float* P = (float*)(ws + (4u << 20));              // 8192*64*4 = 2 MiB
  float* pos = (float*)(ws + (6u << 20));            // 16 KiB
  float* diagE = (float*)(ws + (6u << 20) + 65536);  // 32 KiB
  float* lossAcc = (float*)(ws + (6u << 20) + 131072);
  unsigned int* ticket = (unsigned int*)(ws + (6u << 20) + 131072 + 64);

  k_normalize<<<dim3(NB / 2), dim3(256), 0, stream>>>(xi, xj, Z, diagE, pos,
                                                      lossAcc, ticket);
  k_sym<<<dim3(NTILE), dim3(256), 0, stream>>>(Z, P);
  k_final<<<dim3(32), dim3(256), 0, stream>>>(P, diagE, pos, lossAcc, ticket,
                                              out);
}